// Round 1
// baseline (24.155 us; speedup 1.0000x reference)
//
#include <hip/hip_runtime.h>
#include <math.h>

#define BLOCK 256
#define NP 16          // param sets
#define NANG 28        // 12 rot + 4 ising + 12 entangle half-angle (c,s) pairs per p

// ---- gate helpers: fully unrolled, compile-time masks => all indices constant ----

template<int BP>
__device__ __forceinline__ void gate_ry(float re[16], float im[16], float c, float s) {
    constexpr int M = 1 << BP;
#pragma unroll
    for (int i = 0; i < 16; ++i) {
        if (i & M) continue;
        const int j = i | M;
        float r0 = re[i], q0 = im[i], r1 = re[j], q1 = im[j];
        re[i] = c*r0 - s*r1;  im[i] = c*q0 - s*q1;   // new0 = c a0 - s a1
        re[j] = s*r0 + c*r1;  im[j] = s*q0 + c*q1;   // new1 = s a0 + c a1
    }
}

template<int BP>
__device__ __forceinline__ void gate_rx(float re[16], float im[16], float c, float s) {
    constexpr int M = 1 << BP;
#pragma unroll
    for (int i = 0; i < 16; ++i) {
        if (i & M) continue;
        const int j = i | M;
        float r0 = re[i], q0 = im[i], r1 = re[j], q1 = im[j];
        // new0 = c a0 - i s a1 ; new1 = c a1 - i s a0
        re[i] = c*r0 + s*q1;  im[i] = c*q0 - s*r1;
        re[j] = c*r1 + s*q0;  im[j] = c*q1 - s*r0;
    }
}

template<int BP1, int BP2>
__device__ __forceinline__ void gate_xx(float re[16], float im[16], float c, float s) {
    constexpr int M = (1 << BP1) | (1 << BP2);
#pragma unroll
    for (int i = 0; i < 16; ++i) {
        const int j = i ^ M;           // flip both bits
        if (j < i) continue;           // visit each pair once
        float r0 = re[i], q0 = im[i], r1 = re[j], q1 = im[j];
        // new_a = c a - i s b ; new_b = c b - i s a
        re[i] = c*r0 + s*q1;  im[i] = c*q0 - s*r1;
        re[j] = c*r1 + s*q0;  im[j] = c*q1 - s*r0;
    }
}

template<int CBP, int TBP>
__device__ __forceinline__ void gate_crx(float re[16], float im[16], float c, float s) {
    constexpr int CM = 1 << CBP, TM = 1 << TBP;
#pragma unroll
    for (int i = 0; i < 16; ++i) {
        if (!(i & CM) || (i & TM)) continue;  // control=1, target=0
        const int j = i | TM;
        float r0 = re[i], q0 = im[i], r1 = re[j], q1 = im[j];
        re[i] = c*r0 + s*q1;  im[i] = c*q0 - s*r1;
        re[j] = c*r1 + s*q0;  im[j] = c*q1 - s*r0;
    }
}

__global__ __launch_bounds__(BLOCK) void qnn_kernel(
    const float* __restrict__ x,
    const float* __restrict__ p_rotation,
    const float* __restrict__ p_ising,
    const float* __restrict__ p_entangle,
    float* __restrict__ out, int B)
{
    // per-p gate coefficient table: cs[p*28+k] = (cos(ang/2), sin(ang/2))
    __shared__ float2 cs[NP * NANG];
    const int tid = threadIdx.x;
    for (int i = tid; i < NP * NANG; i += BLOCK) {
        const int p = i / NANG, k = i - p * NANG;
        float ang;
        if (k < 12)       ang = p_rotation[p * 12 + k];
        else if (k < 16)  ang = p_ising[p * 4 + (k - 12)];
        else              ang = p_entangle[p * 12 + (k - 16)];
        float s, c;
        sincosf(0.5f * ang, &s, &c);
        cs[i] = make_float2(c, s);
    }
    __syncthreads();

    const int gid = blockIdx.x * BLOCK + tid;
    const int p = gid & 15;
    const int b = gid >> 4;
    if (b >= B) return;

    // ---- init: normalized RX angle embedding, product state ----
    const float4 xv = reinterpret_cast<const float4*>(x)[b];
    const float inv = rsqrtf(xv.x*xv.x + xv.y*xv.y + xv.z*xv.z + xv.w*xv.w);
    float cw[4], sw[4];
    sincosf(0.5f * xv.x * inv, &sw[0], &cw[0]);
    sincosf(0.5f * xv.y * inv, &sw[1], &cw[1]);
    sincosf(0.5f * xv.z * inv, &sw[2], &cw[2]);
    sincosf(0.5f * xv.w * inv, &sw[3], &cw[3]);

    // amp(idx) = prod_w (bit_w ? -i sin : cos); bit3 = wire0 ... bit0 = wire3
    float re[16], im[16];
#pragma unroll
    for (int idx = 0; idx < 16; ++idx) {
        float m = ((idx & 8) ? sw[0] : cw[0]) * ((idx & 4) ? sw[1] : cw[1])
                * ((idx & 2) ? sw[2] : cw[2]) * ((idx & 1) ? sw[3] : cw[3]);
        const int k = __popc(idx) & 3;  // (-i)^k
        re[idx] = (k == 0) ? m : ((k == 2) ? -m : 0.0f);
        im[idx] = (k == 1) ? -m : ((k == 3) ? m : 0.0f);
    }

    const float2* __restrict__ C = &cs[p * NANG];
    float2 t;
    // layer 1: RY on wires 0..3 (bit 3-w)
    t = C[0];  gate_ry<3>(re, im, t.x, t.y);
    t = C[1];  gate_ry<2>(re, im, t.x, t.y);
    t = C[2];  gate_ry<1>(re, im, t.x, t.y);
    t = C[3];  gate_ry<0>(re, im, t.x, t.y);
    // IsingXX (0,1), (2,3)
    t = C[12]; gate_xx<3,2>(re, im, t.x, t.y);
    t = C[13]; gate_xx<1,0>(re, im, t.x, t.y);
    // layer 2: RX
    t = C[4];  gate_rx<3>(re, im, t.x, t.y);
    t = C[5];  gate_rx<2>(re, im, t.x, t.y);
    t = C[6];  gate_rx<1>(re, im, t.x, t.y);
    t = C[7];  gate_rx<0>(re, im, t.x, t.y);
    // IsingXX (1,2), (3,0)
    t = C[14]; gate_xx<2,1>(re, im, t.x, t.y);
    t = C[15]; gate_xx<0,3>(re, im, t.x, t.y);
    // layer 3: RY
    t = C[8];  gate_ry<3>(re, im, t.x, t.y);
    t = C[9];  gate_ry<2>(re, im, t.x, t.y);
    t = C[10]; gate_ry<1>(re, im, t.x, t.y);
    t = C[11]; gate_ry<0>(re, im, t.x, t.y);
    // CRX entangling layer: pairs (c,t), bit = 3 - wire
    t = C[16]; gate_crx<3,2>(re, im, t.x, t.y);  // (0,1)
    t = C[17]; gate_crx<3,1>(re, im, t.x, t.y);  // (0,2)
    t = C[18]; gate_crx<3,0>(re, im, t.x, t.y);  // (0,3)
    t = C[19]; gate_crx<2,3>(re, im, t.x, t.y);  // (1,0)
    t = C[20]; gate_crx<2,1>(re, im, t.x, t.y);  // (1,2)
    t = C[21]; gate_crx<2,0>(re, im, t.x, t.y);  // (1,3)
    t = C[22]; gate_crx<1,3>(re, im, t.x, t.y);  // (2,0)
    t = C[23]; gate_crx<1,2>(re, im, t.x, t.y);  // (2,1)
    t = C[24]; gate_crx<1,0>(re, im, t.x, t.y);  // (2,3)
    t = C[25]; gate_crx<0,3>(re, im, t.x, t.y);  // (3,0)
    t = C[26]; gate_crx<0,2>(re, im, t.x, t.y);  // (3,1)
    t = C[27]; gate_crx<0,1>(re, im, t.x, t.y);  // (3,2)

    // ---- measurements: Z on wire0 (bit3) and wire2 (bit1) ----
    float z0 = 0.0f, z2 = 0.0f;
#pragma unroll
    for (int idx = 0; idx < 16; ++idx) {
        const float pr = re[idx]*re[idx] + im[idx]*im[idx];
        z0 += (idx & 8) ? -pr : pr;
        z2 += (idx & 2) ? -pr : pr;
    }
    out[b * 32 + p]      = z0;
    out[b * 32 + 16 + p] = z2;
}

extern "C" void kernel_launch(void* const* d_in, const int* in_sizes, int n_in,
                              void* d_out, int out_size, void* d_ws, size_t ws_size,
                              hipStream_t stream) {
    const float* x  = (const float*)d_in[0];
    const float* pr = (const float*)d_in[1];
    const float* pi = (const float*)d_in[2];
    const float* pe = (const float*)d_in[3];
    float* out = (float*)d_out;
    const int B = in_sizes[0] / 4;
    const int total = B * NP;
    const int grid = (total + BLOCK - 1) / BLOCK;
    qnn_kernel<<<grid, BLOCK, 0, stream>>>(x, pr, pi, pe, out, B);
}